// Round 4
// baseline (2485.332 us; speedup 1.0000x reference)
//
#include <hip/hip_runtime.h>
#include <hip/hip_bf16.h>
#include <float.h>

// PatchCore NN-distance: nn_dists[q] = min_m ||query_q - memory_m||, plus max over q.
// Rows are L2-normalized => d2 = 2 - 2*(q.m). Core = bf16 MFMA GEMM with min epilogue.
// R6: 256x256 tile, BK=64, 8 waves (2Mx4N), 8-phase schedule, counted vmcnt(6),
//     st_16x32 LDS swizzle via pre-swizzled global source, setprio around MFMA.
//     vs R5: (a) removed the forced lgkmcnt(0) before each MFMA cluster — the
//     ds_reads are compiler-visible, so the compiler emits staggered per-MFMA
//     lgkmcnt waits (m97 behavior), letting later reads drain under earlier MFMAs
//     instead of serializing a full LDS drain in front of the cluster;
//     (b) phase body reordered STAGE -> LDB -> LDA to match MFMA consume order.
//
// Schedule (per iteration = K-tiles T0=2i in buf0, T1=2i+1 in buf1; stages T2,T3):
//   P1 Q(0,0)b0 + stage buf1.Bc0(T1) | P2 Q(0,1)b0 + buf0.Alo(T2)
//   P3 Q(1,1)b0 + buf0.Bc1(T2)       | P4 Q(1,0)b0 + buf0.Ahi(T2)  -> vmcnt(6)
//   P5 Q(0,0)b1 + buf0.Bc0(T2)       | P6 Q(0,1)b1 + buf1.Alo(T3)
//   P7 Q(1,1)b1 + buf1.Bc1(T3)       | P8 Q(1,0)b1 + buf1.Ahi(T3)  -> vmcnt(6)
// Every stage unit is issued exactly one phase after its last LDS read; every unit
// lands >= one counted vmcnt before its first read. Reads complete before each
// TAIL barrier because their consuming MFMAs (with compiler waits) precede it.

#define QN 4096
#define MN 100000
#define MP 100096             // MN padded to multiple of 256 (391 tiles; pad rows zeroed)
#define DN 1536
#define NT 24                 // K-tiles of 64
#define BK 32                 // fallback kernel K-step
#define NKIT (DN / BK)        // 48 (fallback)

typedef __attribute__((ext_vector_type(8))) short short8;   // bf16x8 MFMA operand
typedef __attribute__((ext_vector_type(4))) float float4v;  // MFMA accumulator
typedef __attribute__((ext_vector_type(4))) short short4v;
typedef __attribute__((address_space(1))) const unsigned g_u32;
typedef __attribute__((address_space(3))) unsigned l_u32;

__device__ __forceinline__ short f2bf(float f) {            // fp32 -> bf16 RNE
    unsigned u = __float_as_uint(f);
    u += 0x7FFFu + ((u >> 16) & 1u);
    return (short)(u >> 16);
}
__device__ __forceinline__ unsigned encf(float f) {         // monotone float->uint
    unsigned u = __float_as_uint(f);
    return (u & 0x80000000u) ? ~u : (u | 0x80000000u);
}
__device__ __forceinline__ float decf(unsigned e) {
    unsigned u = (e & 0x80000000u) ? (e & 0x7FFFFFFFu) : ~e;
    return __uint_as_float(u);
}
__device__ __forceinline__ void gload_lds16(const void* g, void* l) {
    __builtin_amdgcn_global_load_lds((g_u32*)g, (l_u32*)l, 16, 0, 0);
}

__global__ void init_min(unsigned* __restrict__ dminEnc) {
    int i = blockIdx.x * blockDim.x + threadIdx.x;
    if (i < QN) dminEnc[i] = 0xFF7FFFFFu;  // encf(FLT_MAX)
}

// fp32 -> bf16, zero-fill [n_valid, n_total)
__global__ void cvt_bf16(const float* __restrict__ src, short* __restrict__ dst,
                         long n_valid, long n_total) {
    long i = ((long)blockIdx.x * blockDim.x + threadIdx.x) * 4;
    if (i >= n_total) return;
    if (i + 4 <= n_valid) {
        float4 v = *(const float4*)(src + i);
        short4v o = { f2bf(v.x), f2bf(v.y), f2bf(v.z), f2bf(v.w) };
        *(short4v*)(dst + i) = o;
    } else {
        for (int j = 0; j < 4; ++j)
            if (i + j < n_total) dst[i + j] = (i + j < n_valid) ? f2bf(src[i + j]) : 0;
    }
}

// ---------------- fast path: 256^2 8-phase bf16 GEMM ----------------
// LDS subtile layout: [buf][half][R][C][16 rows][32 cols] bf16, 1024 B per subtile.
// st_16x32 swizzle: byte_off ^= ((byte_off>>9)&1)<<5 within each subtile, realized as
// inverse-permuted per-lane GLOBAL source (linear global_load_lds dest lands swizzled)
// + the same XOR on the ds_read side. (Rule #21: both-sides-or-neither.)
#define SUB_OFF(b, h, R, C) ((((((b) * 2 + (h)) * 8 + (R)) * 2) + (C)) * 512)

__global__ __launch_bounds__(512, 2)
void nn_gemm_bf16_256(const short* __restrict__ qB, const short* __restrict__ mB,
                      unsigned* __restrict__ dminEnc)
{
    __shared__ short A_lds[2 * 2 * 8 * 2 * 512];   // 64 KB
    __shared__ short B_lds[2 * 2 * 8 * 2 * 512];   // 64 KB  (total exactly 128 KB)

    const int tid = threadIdx.x;
    const int l   = tid & 63;
    const int w   = tid >> 6;           // wave 0..7
    const int wm  = w >> 2;             // output row-half  (0..1) -> 128 rows
    const int wn  = w & 3;              // output col-quarter (0..3) -> 64 cols
    const int l15 = l & 15;
    const int q4  = l >> 4;

    const int qb = blockIdx.x * 256;
    const int mb = blockIdx.y * 256;

    // ---- staging geometry: each wave stages subtile rows R=f(w) of both C halves ----
    const int rlane = l >> 2;                              // row 0..15 within subtile
    const int csw   = ((l & 3) ^ ((l >> 5) << 1)) * 8;     // inverse-swizzled chunk (shorts)
    const int sh    = w >> 2;                              // staged half (0/1)
    const int saR   = w & 3;                               // A-lo base R (A-hi = +4)
    const int sbR   = ((w >> 1) & 1) * 4 + (w & 1);        // B-c0 base R (B-c1 = +2)

    const short* pAlo = qB + (size_t)(qb + sh * 128 + saR * 16 + rlane) * DN + csw;
    const short* pAhi = pAlo + (size_t)64 * DN;
    const short* pBc0 = mB + (size_t)(mb + sh * 128 + sbR * 16 + rlane) * DN + csw;
    const short* pBc1 = pBc0 + (size_t)32 * DN;

    // ---- fragment-read bases (per-lane, swizzled chunk) ----
    const int inoff = l15 * 64 + ((q4 ^ (((l >> 3) & 1) << 1))) * 16;   // bytes in subtile
    const char* aP = (const char*)A_lds + wm * 16384 + inoff;
    const char* bP = (const char*)B_lds + (wn >> 1) * 16384 + (wn & 1) * 8192 + inoff;

    short8 af[4][2], bf[2][2];
    float4v acc[8][4];
#pragma unroll
    for (int fi = 0; fi < 8; ++fi)
#pragma unroll
        for (int cj = 0; cj < 4; ++cj)
            acc[fi][cj] = (float4v){0.f, 0.f, 0.f, 0.f};

#define STAGE_ALO(b, ko) do { \
        gload_lds16(pAlo + (ko),      &A_lds[SUB_OFF(b, sh, saR,     0)]); \
        gload_lds16(pAlo + (ko) + 32, &A_lds[SUB_OFF(b, sh, saR,     1)]); } while (0)
#define STAGE_AHI(b, ko) do { \
        gload_lds16(pAhi + (ko),      &A_lds[SUB_OFF(b, sh, saR + 4, 0)]); \
        gload_lds16(pAhi + (ko) + 32, &A_lds[SUB_OFF(b, sh, saR + 4, 1)]); } while (0)
#define STAGE_BC0(b, ko) do { \
        gload_lds16(pBc0 + (ko),      &B_lds[SUB_OFF(b, sh, sbR,     0)]); \
        gload_lds16(pBc0 + (ko) + 32, &B_lds[SUB_OFF(b, sh, sbR,     1)]); } while (0)
#define STAGE_BC1(b, ko) do { \
        gload_lds16(pBc1 + (ko),      &B_lds[SUB_OFF(b, sh, sbR + 2, 0)]); \
        gload_lds16(pBc1 + (ko) + 32, &B_lds[SUB_OFF(b, sh, sbR + 2, 1)]); } while (0)

#define LDA(b, RH) do { _Pragma("unroll") \
        for (int m_ = 0; m_ < 4; ++m_) { \
            af[m_][0] = *(const short8*)(aP + (b) * 32768 + ((RH) * 4 + m_) * 2048); \
            af[m_][1] = *(const short8*)(aP + (b) * 32768 + ((RH) * 4 + m_) * 2048 + 1024); } } while (0)
#define LDB(b, CH) do { _Pragma("unroll") \
        for (int n_ = 0; n_ < 2; ++n_) { \
            bf[n_][0] = *(const short8*)(bP + (b) * 32768 + ((CH) * 2 + n_) * 2048); \
            bf[n_][1] = *(const short8*)(bP + (b) * 32768 + ((CH) * 2 + n_) * 2048 + 1024); } } while (0)

#define MMA(RH, CH) do { _Pragma("unroll") \
        for (int m_ = 0; m_ < 4; ++m_) { _Pragma("unroll") \
            for (int n_ = 0; n_ < 2; ++n_) { \
                acc[(RH) * 4 + m_][(CH) * 2 + n_] = __builtin_amdgcn_mfma_f32_16x16x32_bf16( \
                    af[m_][0], bf[n_][0], acc[(RH) * 4 + m_][(CH) * 2 + n_], 0, 0, 0); \
                acc[(RH) * 4 + m_][(CH) * 2 + n_] = __builtin_amdgcn_mfma_f32_16x16x32_bf16( \
                    af[m_][1], bf[n_][1], acc[(RH) * 4 + m_][(CH) * 2 + n_], 0, 0, 0); } } } while (0)

// No forced lgkmcnt(0): the ds_reads are compiler-visible, so the compiler emits
// staggered per-MFMA lgkmcnt waits; all reads are consumed (and thus drained)
// before the TAIL barrier, which keeps the stage-after-read hazard window safe.
#define MID(RH, CH) \
        __builtin_amdgcn_s_barrier(); \
        __builtin_amdgcn_s_setprio(1); \
        MMA(RH, CH); \
        __builtin_amdgcn_s_setprio(0);
#define TAIL \
        __builtin_amdgcn_s_barrier();
#define TAIL_VM6 \
        asm volatile("s_waitcnt vmcnt(6)" ::: "memory"); \
        __builtin_amdgcn_s_barrier();
#define TAIL_VM0 \
        asm volatile("s_waitcnt vmcnt(0)" ::: "memory"); \
        __builtin_amdgcn_s_barrier();

    // ---- prologue: tile0 -> buf0 (4 units), tile1 -> buf1 (Alo,Bc1,Ahi) ----
    STAGE_ALO(0, 0); STAGE_AHI(0, 0); STAGE_BC0(0, 0); STAGE_BC1(0, 0);
    STAGE_ALO(1, 64); STAGE_BC1(1, 64); STAGE_AHI(1, 64);
    asm volatile("s_waitcnt vmcnt(6)" ::: "memory");
    __builtin_amdgcn_s_barrier();

    for (int it = 0; it < NT / 2 - 1; ++it) {
        const int kT1 = (it * 2 + 1) * 64;
        const int kT2 = kT1 + 64;
        const int kT3 = kT1 + 128;
        // P1
        STAGE_BC0(1, kT1); LDB(0, 0); LDA(0, 0);
        MID(0, 0) TAIL
        // P2
        STAGE_ALO(0, kT2); LDB(0, 1);
        MID(0, 1) TAIL
        // P3
        STAGE_BC1(0, kT2); LDA(0, 1);
        MID(1, 1) TAIL
        // P4
        STAGE_AHI(0, kT2); LDB(0, 0);
        MID(1, 0) TAIL_VM6
        // P5
        STAGE_BC0(0, kT2); LDB(1, 0); LDA(1, 0);
        MID(0, 0) TAIL
        // P6
        STAGE_ALO(1, kT3); LDB(1, 1);
        MID(0, 1) TAIL
        // P7
        STAGE_BC1(1, kT3); LDA(1, 1);
        MID(1, 1) TAIL
        // P8
        STAGE_AHI(1, kT3); LDB(1, 0);
        MID(1, 0) TAIL_VM6
    }
    // ---- final iteration (tiles NT-2, NT-1): only P1's Bc0 stage remains ----
    STAGE_BC0(1, (NT - 1) * 64); LDB(0, 0); LDA(0, 0);
    MID(0, 0) TAIL
    LDB(0, 1);
    MID(0, 1) TAIL
    LDA(0, 1);
    MID(1, 1) TAIL
    LDB(0, 0);
    MID(1, 0) TAIL_VM0
    LDB(1, 0); LDA(1, 0);
    MID(0, 0) TAIL
    LDB(1, 1);
    MID(0, 1) TAIL
    LDA(1, 1);
    MID(1, 1) TAIL
    LDB(1, 0);
    MID(1, 0)

#undef STAGE_ALO
#undef STAGE_AHI
#undef STAGE_BC0
#undef STAGE_BC1
#undef LDA
#undef LDB
#undef MMA
#undef MID
#undef TAIL
#undef TAIL_VM6
#undef TAIL_VM0

    // ---- epilogue: d2 = 2 - 2*s, min over this block's 256 cols per query row ----
    // A_lds is dead after the K-loop: alias its first 1 KB as the per-block qmin.
    // __syncthreads (full waitcnt + barrier) guarantees all LDS traffic drained.
    unsigned* qmin = (unsigned*)A_lds;
    __syncthreads();
    if (tid < 256) qmin[tid] = 0xFFFFFFFFu;
    __syncthreads();

    // C/D 16x16 layout: col = lane&15 (memory), row = (lane>>4)*4 + reg (query).
#pragma unroll
    for (int fi = 0; fi < 8; ++fi) {
#pragma unroll
        for (int r = 0; r < 4; ++r) {
            float v = FLT_MAX;
#pragma unroll
            for (int cj = 0; cj < 4; ++cj) {
                const int gcol = mb + wn * 64 + cj * 16 + l15;
                const float d2 = fmaf(-2.0f, acc[fi][cj][r], 2.0f);
                v = fminf(v, (gcol < MN) ? d2 : FLT_MAX);
            }
            v = fminf(v, __shfl_xor(v, 1));
            v = fminf(v, __shfl_xor(v, 2));
            v = fminf(v, __shfl_xor(v, 4));
            v = fminf(v, __shfl_xor(v, 8));
            if (l15 == 0)
                atomicMin(&qmin[wm * 128 + fi * 16 + q4 * 4 + r], encf(v));
        }
    }
    __syncthreads();
    if (tid < 256) atomicMin(&dminEnc[qb + tid], qmin[tid]);
}

// ---------------- fallback path (fp32 inputs, small workspace) -----------------
#define LDSS 40
__global__ __launch_bounds__(256, 2)
void nn_gemm_f32(const float* __restrict__ query, const float* __restrict__ memory,
                 unsigned* __restrict__ dminEnc)
{
    __shared__ __align__(16) short As[128 * LDSS];
    __shared__ __align__(16) short Bs[128 * LDSS];
    __shared__ unsigned qmin[128];

    const int tid = threadIdx.x, lane = tid & 63, wave = tid >> 6;
    const int wrow = wave >> 1, wcol = wave & 1, quad = lane >> 4, l16 = lane & 15;
    const int qb = blockIdx.x * 128, mb = blockIdx.y * 128;
    if (tid < 128) qmin[tid] = 0xFFFFFFFFu;

    int rowS[4], c4S[4];
    const float *aPtr[4], *bPtr[4];
    bool bValid[4];
#pragma unroll
    for (int s = 0; s < 4; ++s) {
        int idx = s * 256 + tid, row = idx >> 3, c4 = idx & 7;
        rowS[s] = row; c4S[s] = c4;
        aPtr[s] = query + (size_t)(qb + row) * DN + c4 * 4;
        int gr = mb + row;
        bValid[s] = (gr < MN);
        bPtr[s] = memory + (size_t)(bValid[s] ? gr : 0) * DN + c4 * 4;
    }
    float4 aReg[4], bReg[4];
#pragma unroll
    for (int s = 0; s < 4; ++s) {
        aReg[s] = *(const float4*)(aPtr[s]);
        bReg[s] = bValid[s] ? *(const float4*)(bPtr[s]) : make_float4(0.f, 0.f, 0.f, 0.f);
    }
    float4v acc[4][4];
#pragma unroll
    for (int mi = 0; mi < 4; ++mi)
#pragma unroll
        for (int ni = 0; ni < 4; ++ni) acc[mi][ni] = (float4v){0.f, 0.f, 0.f, 0.f};

    for (int kk = 0; kk < NKIT; ++kk) {
#pragma unroll
        for (int s = 0; s < 4; ++s) {
            short4v pa = { f2bf(aReg[s].x), f2bf(aReg[s].y), f2bf(aReg[s].z), f2bf(aReg[s].w) };
            short4v pb = { f2bf(bReg[s].x), f2bf(bReg[s].y), f2bf(bReg[s].z), f2bf(bReg[s].w) };
            *(short4v*)&As[rowS[s] * LDSS + c4S[s] * 4] = pa;
            *(short4v*)&Bs[rowS[s] * LDSS + c4S[s] * 4] = pb;
        }
        __syncthreads();
        if (kk + 1 < NKIT) {
            const int ko = (kk + 1) * BK;
#pragma unroll
            for (int s = 0; s < 4; ++s) {
                aReg[s] = *(const float4*)(aPtr[s] + ko);
                bReg[s] = bValid[s] ? *(const float4*)(bPtr[s] + ko)
                                    : make_float4(0.f, 0.f, 0.f, 0.f);
            }
        }
        short8 af[4], bfr[4];
#pragma unroll
        for (int mi = 0; mi < 4; ++mi)
            af[mi] = *(const short8*)&As[(wrow * 64 + mi * 16 + l16) * LDSS + quad * 8];
#pragma unroll
        for (int ni = 0; ni < 4; ++ni)
            bfr[ni] = *(const short8*)&Bs[(wcol * 64 + ni * 16 + l16) * LDSS + quad * 8];
#pragma unroll
        for (int mi = 0; mi < 4; ++mi)
#pragma unroll
            for (int ni = 0; ni < 4; ++ni)
                acc[mi][ni] = __builtin_amdgcn_mfma_f32_16x16x32_bf16(
                    af[mi], bfr[ni], acc[mi][ni], 0, 0, 0);
        __syncthreads();
    }
#pragma unroll
    for (int mi = 0; mi < 4; ++mi) {
#pragma unroll
        for (int r = 0; r < 4; ++r) {
            float v = FLT_MAX;
#pragma unroll
            for (int ni = 0; ni < 4; ++ni) {
                int gcol = mb + wcol * 64 + ni * 16 + l16;
                float d2 = fmaf(-2.0f, acc[mi][ni][r], 2.0f);
                v = fminf(v, (gcol < MN) ? d2 : FLT_MAX);
            }
            v = fminf(v, __shfl_xor(v, 1));
            v = fminf(v, __shfl_xor(v, 2));
            v = fminf(v, __shfl_xor(v, 4));
            v = fminf(v, __shfl_xor(v, 8));
            if (l16 == 0)
                atomicMin(&qmin[wrow * 64 + mi * 16 + quad * 4 + r], encf(v));
        }
    }
    __syncthreads();
    if (tid < 128) atomicMin(&dminEnc[qb + tid], qmin[tid]);
}

__global__ void finalize(const unsigned* __restrict__ dminEnc, float* __restrict__ out) {
    __shared__ float red[256];
    const int tid = threadIdx.x;
    float mx = 0.f;
    for (int i = tid; i < QN; i += 256) {
        float d2 = decf(dminEnc[i]);
        float d = sqrtf(fmaxf(d2, 0.f));
        out[i] = d;
        mx = fmaxf(mx, d);
    }
    red[tid] = mx;
    __syncthreads();
    for (int s = 128; s > 0; s >>= 1) {
        if (tid < s) red[tid] = fmaxf(red[tid], red[tid + s]);
        __syncthreads();
    }
    if (tid == 0) out[QN] = red[0];
}

extern "C" void kernel_launch(void* const* d_in, const int* in_sizes, int n_in,
                              void* d_out, int out_size, void* d_ws, size_t ws_size,
                              hipStream_t stream)
{
    const float* query  = (const float*)d_in[0];
    const float* memory = (const float*)d_in[1];
    float* out = (float*)d_out;

    const size_t memB_elems = (size_t)MP * DN;          // padded bf16 memory
    const size_t qB_elems   = (size_t)QN * DN;
    const size_t need = memB_elems * 2 + qB_elems * 2 + (size_t)QN * 4;

    if (ws_size >= need) {
        short* mB = (short*)d_ws;
        short* qB = mB + memB_elems;
        unsigned* dminEnc = (unsigned*)(qB + qB_elems);

        hipLaunchKernelGGL(init_min, dim3((QN + 255) / 256), dim3(256), 0, stream, dminEnc);
        {
            long nv = (long)MN * DN, nt = (long)memB_elems;
            int blocks = (int)((nt / 4 + 255) / 256);
            hipLaunchKernelGGL(cvt_bf16, dim3(blocks), dim3(256), 0, stream,
                               memory, mB, nv, nt);
        }
        {
            long nv = (long)qB_elems, nt = (long)qB_elems;
            int blocks = (int)((nt / 4 + 255) / 256);
            hipLaunchKernelGGL(cvt_bf16, dim3(blocks), dim3(256), 0, stream,
                               query, qB, nv, nt);
        }
        hipLaunchKernelGGL(nn_gemm_bf16_256, dim3(QN / 256, MP / 256), dim3(512), 0, stream,
                           qB, mB, dminEnc);
        hipLaunchKernelGGL(finalize, dim3(1), dim3(256), 0, stream, dminEnc, out);
    } else {
        unsigned* dminEnc = (unsigned*)d_ws;
        hipLaunchKernelGGL(init_min, dim3((QN + 255) / 256), dim3(256), 0, stream, dminEnc);
        hipLaunchKernelGGL(nn_gemm_f32, dim3(QN / 128, (MN + 127) / 128), dim3(256), 0, stream,
                           query, memory, dminEnc);
        hipLaunchKernelGGL(finalize, dim3(1), dim3(256), 0, stream, dminEnc, out);
    }
}

// Round 5
// 2120.819 us; speedup vs baseline: 1.1719x; 1.1719x over previous
//
#include <hip/hip_runtime.h>
#include <hip/hip_bf16.h>
#include <float.h>

// PatchCore NN-distance: nn_dists[q] = min_m ||query_q - memory_m||, plus max over q.
// Rows are L2-normalized => d2 = 2 - 2*(q.m). Core = bf16 MFMA GEMM with min epilogue.
// R7: read-ahead pipeline. The R4-R6 2-barrier phases serialized LDS reads (~500cy)
//     with MFMA (~620cy) -> 1617cy/phase. Now reads for phase p+1 issue INSIDE phase
//     p's MFMA window into register-disjoint sets, so the LDS pipe drains under the
//     matrix pipe:
//     - bf double-buffered (sets alternate P1..P8: S0,S1,S1,S0,S1,S0,S0,S1)
//     - af single-set, rotated per-m right after the MFMA group that last uses it
//     - ONE barrier per window (reads+MFMA share a region; MID/TAIL collapse)
//     - vmcnt(4) at W3/W7 ends BEFORE the boundary barrier (per-wave counts need a
//       barrier to publish other waves' staging); prologue vmcnt(6); final vmcnt(0)@F3.
//     Same-window read-vs-stage pairs all disjoint (R0-3 vs R4-7 / BC0-rows vs
//     BC1-rows / other buffer); anti-deps >= 2 windows (read drained by consume-wait
//     before its wave can cross the next boundary barrier).

#define QN 4096
#define MN 100000
#define MP 100096             // MN padded to multiple of 256 (391 tiles; pad rows zeroed)
#define DN 1536
#define NT 24                 // K-tiles of 64
#define BK 32                 // fallback kernel K-step
#define NKIT (DN / BK)        // 48 (fallback)

typedef __attribute__((ext_vector_type(8))) short short8;   // bf16x8 MFMA operand
typedef __attribute__((ext_vector_type(4))) float float4v;  // MFMA accumulator
typedef __attribute__((ext_vector_type(4))) short short4v;
typedef __attribute__((address_space(1))) const unsigned g_u32;
typedef __attribute__((address_space(3))) unsigned l_u32;

__device__ __forceinline__ short f2bf(float f) {            // fp32 -> bf16 RNE
    unsigned u = __float_as_uint(f);
    u += 0x7FFFu + ((u >> 16) & 1u);
    return (short)(u >> 16);
}
__device__ __forceinline__ unsigned encf(float f) {         // monotone float->uint
    unsigned u = __float_as_uint(f);
    return (u & 0x80000000u) ? ~u : (u | 0x80000000u);
}
__device__ __forceinline__ float decf(unsigned e) {
    unsigned u = (e & 0x80000000u) ? (e & 0x7FFFFFFFu) : ~e;
    return __uint_as_float(u);
}
__device__ __forceinline__ void gload_lds16(const void* g, void* l) {
    __builtin_amdgcn_global_load_lds((g_u32*)g, (l_u32*)l, 16, 0, 0);
}

__global__ void init_min(unsigned* __restrict__ dminEnc) {
    int i = blockIdx.x * blockDim.x + threadIdx.x;
    if (i < QN) dminEnc[i] = 0xFF7FFFFFu;  // encf(FLT_MAX)
}

// fp32 -> bf16, zero-fill [n_valid, n_total)
__global__ void cvt_bf16(const float* __restrict__ src, short* __restrict__ dst,
                         long n_valid, long n_total) {
    long i = ((long)blockIdx.x * blockDim.x + threadIdx.x) * 4;
    if (i >= n_total) return;
    if (i + 4 <= n_valid) {
        float4 v = *(const float4*)(src + i);
        short4v o = { f2bf(v.x), f2bf(v.y), f2bf(v.z), f2bf(v.w) };
        *(short4v*)(dst + i) = o;
    } else {
        for (int j = 0; j < 4; ++j)
            if (i + j < n_total) dst[i + j] = (i + j < n_valid) ? f2bf(src[i + j]) : 0;
    }
}

// ---------------- fast path: 256^2 read-ahead bf16 GEMM ----------------
// LDS subtile layout: [buf][half][R][C][16 rows][32 cols] bf16, 1024 B per subtile.
// st_16x32 swizzle via inverse-permuted global source + XOR'd ds_read (rule #21).
#define SUB_OFF(b, h, R, C) ((((((b) * 2 + (h)) * 8 + (R)) * 2) + (C)) * 512)

__global__ __launch_bounds__(512, 2)
void nn_gemm_bf16_256(const short* __restrict__ qB, const short* __restrict__ mB,
                      unsigned* __restrict__ dminEnc)
{
    __shared__ short A_lds[2 * 2 * 8 * 2 * 512];   // 64 KB
    __shared__ short B_lds[2 * 2 * 8 * 2 * 512];   // 64 KB  (total exactly 128 KB)

    const int tid = threadIdx.x;
    const int l   = tid & 63;
    const int w   = tid >> 6;           // wave 0..7
    const int wm  = w >> 2;             // output row-half  (0..1) -> 128 rows
    const int wn  = w & 3;              // output col-quarter (0..3) -> 64 cols
    const int l15 = l & 15;
    const int q4  = l >> 4;

    const int qb = blockIdx.x * 256;
    const int mb = blockIdx.y * 256;

    // ---- staging geometry ----
    const int rlane = l >> 2;                              // row 0..15 within subtile
    const int csw   = ((l & 3) ^ ((l >> 5) << 1)) * 8;     // inverse-swizzled chunk (shorts)
    const int sh    = w >> 2;                              // staged half (0/1)
    const int saR   = w & 3;                               // A-lo base R (A-hi = +4)
    const int sbR   = ((w >> 1) & 1) * 4 + (w & 1);        // B-c0 base R (B-c1 = +2)

    const short* pAlo = qB + (size_t)(qb + sh * 128 + saR * 16 + rlane) * DN + csw;
    const short* pAhi = pAlo + (size_t)64 * DN;
    const short* pBc0 = mB + (size_t)(mb + sh * 128 + sbR * 16 + rlane) * DN + csw;
    const short* pBc1 = pBc0 + (size_t)32 * DN;

    // ---- fragment-read bases (per-lane, swizzled chunk) ----
    const int inoff = l15 * 64 + ((q4 ^ (((l >> 3) & 1) << 1))) * 16;   // bytes in subtile
    const char* aP = (const char*)A_lds + wm * 16384 + inoff;
    const char* bP = (const char*)B_lds + (wn >> 1) * 16384 + (wn & 1) * 8192 + inoff;

    short8 af[4][2];          // single set, rotated
    short8 bf[2][2][2];       // [set][n][k-half], sets alternate
    float4v acc[8][4];
#pragma unroll
    for (int fi = 0; fi < 8; ++fi)
#pragma unroll
        for (int cj = 0; cj < 4; ++cj)
            acc[fi][cj] = (float4v){0.f, 0.f, 0.f, 0.f};

#define STAGE_ALO(b, ko) do { \
        gload_lds16(pAlo + (ko),      &A_lds[SUB_OFF(b, sh, saR,     0)]); \
        gload_lds16(pAlo + (ko) + 32, &A_lds[SUB_OFF(b, sh, saR,     1)]); } while (0)
#define STAGE_AHI(b, ko) do { \
        gload_lds16(pAhi + (ko),      &A_lds[SUB_OFF(b, sh, saR + 4, 0)]); \
        gload_lds16(pAhi + (ko) + 32, &A_lds[SUB_OFF(b, sh, saR + 4, 1)]); } while (0)
#define STAGE_BC0(b, ko) do { \
        gload_lds16(pBc0 + (ko),      &B_lds[SUB_OFF(b, sh, sbR,     0)]); \
        gload_lds16(pBc0 + (ko) + 32, &B_lds[SUB_OFF(b, sh, sbR,     1)]); } while (0)
#define STAGE_BC1(b, ko) do { \
        gload_lds16(pBc1 + (ko),      &B_lds[SUB_OFF(b, sh, sbR + 2, 0)]); \
        gload_lds16(pBc1 + (ko) + 32, &B_lds[SUB_OFF(b, sh, sbR + 2, 1)]); } while (0)

#define RD_B(S, b, CH) do { _Pragma("unroll") \
        for (int n_ = 0; n_ < 2; ++n_) { \
            bf[S][n_][0] = *(const short8*)(bP + (b) * 32768 + ((CH) * 2 + n_) * 2048); \
            bf[S][n_][1] = *(const short8*)(bP + (b) * 32768 + ((CH) * 2 + n_) * 2048 + 1024); } } while (0)
#define RD_A1(b, RH, m) do { \
        af[m][0] = *(const short8*)(aP + (b) * 32768 + ((RH) * 4 + (m)) * 2048); \
        af[m][1] = *(const short8*)(aP + (b) * 32768 + ((RH) * 4 + (m)) * 2048 + 1024); } while (0)

#define MMA_G(S, RH, CH, m) do { _Pragma("unroll") \
        for (int n_ = 0; n_ < 2; ++n_) { \
            acc[(RH) * 4 + (m)][(CH) * 2 + n_] = __builtin_amdgcn_mfma_f32_16x16x32_bf16( \
                af[m][0], bf[S][n_][0], acc[(RH) * 4 + (m)][(CH) * 2 + n_], 0, 0, 0); \
            acc[(RH) * 4 + (m)][(CH) * 2 + n_] = __builtin_amdgcn_mfma_f32_16x16x32_bf16( \
                af[m][1], bf[S][n_][1], acc[(RH) * 4 + (m)][(CH) * 2 + n_], 0, 0, 0); } } while (0)

#define BAR   __builtin_amdgcn_s_barrier()
#define PRIO1 __builtin_amdgcn_s_setprio(1)
#define PRIO0 __builtin_amdgcn_s_setprio(0)
#define VM4   asm volatile("s_waitcnt vmcnt(4)" ::: "memory")
#define VM6   asm volatile("s_waitcnt vmcnt(6)" ::: "memory")
#define VM0   asm volatile("s_waitcnt vmcnt(0)" ::: "memory")

    // ---- prologue: buf0 full (8 loads), buf1 partial ALO/BC1/AHI (6 loads) ----
    STAGE_ALO(0, 0); STAGE_AHI(0, 0); STAGE_BC0(0, 0); STAGE_BC1(0, 0);
    STAGE_ALO(1, 64); STAGE_BC1(1, 64); STAGE_AHI(1, 64);
    VM6;                       // buf0 landed (6 buf1 loads remain in flight)
    BAR;
    // P1 operand set: bfA <- B(0,CH0), af <- A(0,RH0)
    RD_B(0, 0, 0);
    RD_A1(0, 0, 0); RD_A1(0, 0, 1); RD_A1(0, 0, 2); RD_A1(0, 0, 3);

    for (int it = 0; it < NT / 2 - 1; ++it) {
        const int kT1 = (it * 2 + 1) * 64;
        const int kT2 = kT1 + 64;
        const int kT3 = kT1 + 128;
        // W1: P1 = Q(0,0) buf0 [S0]; read bfB <- B(0,CH1)
        RD_B(1, 0, 1); STAGE_BC0(1, kT1);
        PRIO1; MMA_G(0,0,0,0); MMA_G(0,0,0,1); MMA_G(0,0,0,2); MMA_G(0,0,0,3); PRIO0;
        BAR;
        // W2: P2 = Q(0,1) buf0 [S1]; af-rotate -> A(0,RH1)
        PRIO1;
        MMA_G(1,0,1,0); RD_A1(0,1,0);
        MMA_G(1,0,1,1); RD_A1(0,1,1);
        MMA_G(1,0,1,2); RD_A1(0,1,2);
        MMA_G(1,0,1,3); RD_A1(0,1,3);
        PRIO0; STAGE_ALO(0, kT2);
        BAR;
        // W3: P3 = Q(1,1) buf0 [S1]; read bfA <- B(0,CH0)
        RD_B(0, 0, 0); STAGE_BC1(0, kT2);
        PRIO1; MMA_G(1,1,1,0); MMA_G(1,1,1,1); MMA_G(1,1,1,2); MMA_G(1,1,1,3); PRIO0;
        VM4;                   // drains buf1 units {prevW6,prevW7,prevW8,W1} for W4 reads
        BAR;
        // W4: P4 = Q(1,0) buf0 [S0]; read bfB <- B(1,CH0); af-rotate -> A(1,RH0)
        RD_B(1, 1, 0); STAGE_AHI(0, kT2);
        PRIO1;
        MMA_G(0,1,0,0); RD_A1(1,0,0);
        MMA_G(0,1,0,1); RD_A1(1,0,1);
        MMA_G(0,1,0,2); RD_A1(1,0,2);
        MMA_G(0,1,0,3); RD_A1(1,0,3);
        PRIO0; BAR;
        // W5: P5 = Q(0,0) buf1 [S1]; read bfA <- B(1,CH1)
        RD_B(0, 1, 1); STAGE_BC0(0, kT2);
        PRIO1; MMA_G(1,0,0,0); MMA_G(1,0,0,1); MMA_G(1,0,0,2); MMA_G(1,0,0,3); PRIO0;
        BAR;
        // W6: P6 = Q(0,1) buf1 [S0]; af-rotate -> A(1,RH1)
        STAGE_ALO(1, kT3);
        PRIO1;
        MMA_G(0,0,1,0); RD_A1(1,1,0);
        MMA_G(0,0,1,1); RD_A1(1,1,1);
        MMA_G(0,0,1,2); RD_A1(1,1,2);
        MMA_G(0,0,1,3); RD_A1(1,1,3);
        PRIO0; BAR;
        // W7: P7 = Q(1,1) buf1 [S0]; read bfB <- B(1,CH0)
        RD_B(1, 1, 0); STAGE_BC1(1, kT3);
        PRIO1; MMA_G(0,1,1,0); MMA_G(0,1,1,1); MMA_G(0,1,1,2); MMA_G(0,1,1,3); PRIO0;
        VM4;                   // drains buf0 units {W2,W3,W4,W5} for W8 reads
        BAR;
        // W8: P8 = Q(1,0) buf1 [S1]; read bfA <- B(0,CH0)[T2]; af-rotate -> A(0,RH0)[T2]
        RD_B(0, 0, 0); STAGE_AHI(1, kT3);
        PRIO1;
        MMA_G(1,1,0,0); RD_A1(0,0,0);
        MMA_G(1,1,0,1); RD_A1(0,0,1);
        MMA_G(1,1,0,2); RD_A1(0,0,2);
        MMA_G(1,1,0,3); RD_A1(0,0,3);
        PRIO0; BAR;
    }
    // ---- final iteration (tiles NT-2 in buf0, NT-1 in buf1) ----
    // F1
    RD_B(1, 0, 1); STAGE_BC0(1, (NT - 1) * 64);
    PRIO1; MMA_G(0,0,0,0); MMA_G(0,0,0,1); MMA_G(0,0,0,2); MMA_G(0,0,0,3); PRIO0;
    BAR;
    // F2
    PRIO1;
    MMA_G(1,0,1,0); RD_A1(0,1,0);
    MMA_G(1,0,1,1); RD_A1(0,1,1);
    MMA_G(1,0,1,2); RD_A1(0,1,2);
    MMA_G(1,0,1,3); RD_A1(0,1,3);
    PRIO0; BAR;
    // F3
    RD_B(0, 0, 0);
    PRIO1; MMA_G(1,1,1,0); MMA_G(1,1,1,1); MMA_G(1,1,1,2); MMA_G(1,1,1,3); PRIO0;
    VM0;                        // buf1 (tile NT-1) fully landed
    BAR;
    // F4
    RD_B(1, 1, 0);
    PRIO1;
    MMA_G(0,1,0,0); RD_A1(1,0,0);
    MMA_G(0,1,0,1); RD_A1(1,0,1);
    MMA_G(0,1,0,2); RD_A1(1,0,2);
    MMA_G(0,1,0,3); RD_A1(1,0,3);
    PRIO0; BAR;
    // F5
    RD_B(0, 1, 1);
    PRIO1; MMA_G(1,0,0,0); MMA_G(1,0,0,1); MMA_G(1,0,0,2); MMA_G(1,0,0,3); PRIO0;
    BAR;
    // F6
    PRIO1;
    MMA_G(0,0,1,0); RD_A1(1,1,0);
    MMA_G(0,0,1,1); RD_A1(1,1,1);
    MMA_G(0,0,1,2); RD_A1(1,1,2);
    MMA_G(0,0,1,3); RD_A1(1,1,3);
    PRIO0; BAR;
    // F7
    RD_B(1, 1, 0);
    PRIO1; MMA_G(0,1,1,0); MMA_G(0,1,1,1); MMA_G(0,1,1,2); MMA_G(0,1,1,3); PRIO0;
    BAR;
    // F8
    PRIO1; MMA_G(1,1,0,0); MMA_G(1,1,0,1); MMA_G(1,1,0,2); MMA_G(1,1,0,3); PRIO0;

#undef STAGE_ALO
#undef STAGE_AHI
#undef STAGE_BC0
#undef STAGE_BC1
#undef RD_B
#undef RD_A1
#undef MMA_G
#undef BAR
#undef PRIO1
#undef PRIO0
#undef VM4
#undef VM6
#undef VM0

    // ---- epilogue: d2 = 2 - 2*s, min over this block's 256 cols per query row ----
    // A_lds is dead after the K-loop: alias its first 1 KB as the per-block qmin.
    unsigned* qmin = (unsigned*)A_lds;
    __syncthreads();
    if (tid < 256) qmin[tid] = 0xFFFFFFFFu;
    __syncthreads();

    // C/D 16x16 layout: col = lane&15 (memory), row = (lane>>4)*4 + reg (query).
#pragma unroll
    for (int fi = 0; fi < 8; ++fi) {
#pragma unroll
        for (int r = 0; r < 4; ++r) {
            float v = FLT_MAX;
#pragma unroll
            for (int cj = 0; cj < 4; ++cj) {
                const int gcol = mb + wn * 64 + cj * 16 + l15;
                const float d2 = fmaf(-2.0f, acc[fi][cj][r], 2.0f);
                v = fminf(v, (gcol < MN) ? d2 : FLT_MAX);
            }
            v = fminf(v, __shfl_xor(v, 1));
            v = fminf(v, __shfl_xor(v, 2));
            v = fminf(v, __shfl_xor(v, 4));
            v = fminf(v, __shfl_xor(v, 8));
            if (l15 == 0)
                atomicMin(&qmin[wm * 128 + fi * 16 + q4 * 4 + r], encf(v));
        }
    }
    __syncthreads();
    if (tid < 256) atomicMin(&dminEnc[qb + tid], qmin[tid]);
}

// ---------------- fallback path (fp32 inputs, small workspace) -----------------
#define LDSS 40
__global__ __launch_bounds__(256, 2)
void nn_gemm_f32(const float* __restrict__ query, const float* __restrict__ memory,
                 unsigned* __restrict__ dminEnc)
{
    __shared__ __align__(16) short As[128 * LDSS];
    __shared__ __align__(16) short Bs[128 * LDSS];
    __shared__ unsigned qmin[128];

    const int tid = threadIdx.x, lane = tid & 63, wave = tid >> 6;
    const int wrow = wave >> 1, wcol = wave & 1, quad = lane >> 4, l16 = lane & 15;
    const int qb = blockIdx.x * 128, mb = blockIdx.y * 128;
    if (tid < 128) qmin[tid] = 0xFFFFFFFFu;

    int rowS[4], c4S[4];
    const float *aPtr[4], *bPtr[4];
    bool bValid[4];
#pragma unroll
    for (int s = 0; s < 4; ++s) {
        int idx = s * 256 + tid, row = idx >> 3, c4 = idx & 7;
        rowS[s] = row; c4S[s] = c4;
        aPtr[s] = query + (size_t)(qb + row) * DN + c4 * 4;
        int gr = mb + row;
        bValid[s] = (gr < MN);
        bPtr[s] = memory + (size_t)(bValid[s] ? gr : 0) * DN + c4 * 4;
    }
    float4 aReg[4], bReg[4];
#pragma unroll
    for (int s = 0; s < 4; ++s) {
        aReg[s] = *(const float4*)(aPtr[s]);
        bReg[s] = bValid[s] ? *(const float4*)(bPtr[s]) : make_float4(0.f, 0.f, 0.f, 0.f);
    }
    float4v acc[4][4];
#pragma unroll
    for (int mi = 0; mi < 4; ++mi)
#pragma unroll
        for (int ni = 0; ni < 4; ++ni) acc[mi][ni] = (float4v){0.f, 0.f, 0.f, 0.f};

    for (int kk = 0; kk < NKIT; ++kk) {
#pragma unroll
        for (int s = 0; s < 4; ++s) {
            short4v pa = { f2bf(aReg[s].x), f2bf(aReg[s].y), f2bf(aReg[s].z), f2bf(aReg[s].w) };
            short4v pb = { f2bf(bReg[s].x), f2bf(bReg[s].y), f2bf(bReg[s].z), f2bf(bReg[s].w) };
            *(short4v*)&As[rowS[s] * LDSS + c4S[s] * 4] = pa;
            *(short4v*)&Bs[rowS[s] * LDSS + c4S[s] * 4] = pb;
        }
        __syncthreads();
        if (kk + 1 < NKIT) {
            const int ko = (kk + 1) * BK;
#pragma unroll
            for (int s = 0; s < 4; ++s) {
                aReg[s] = *(const float4*)(aPtr[s] + ko);
                bReg[s] = bValid[s] ? *(const float4*)(bPtr[s] + ko)
                                    : make_float4(0.f, 0.f, 0.f, 0.f);
            }
        }
        short8 af[4], bfr[4];
#pragma unroll
        for (int mi = 0; mi < 4; ++mi)
            af[mi] = *(const short8*)&As[(wrow * 64 + mi * 16 + l16) * LDSS + quad * 8];
#pragma unroll
        for (int ni = 0; ni < 4; ++ni)
            bfr[ni] = *(const short8*)&Bs[(wcol * 64 + ni * 16 + l16) * LDSS + quad * 8];
#pragma unroll
        for (int mi = 0; mi < 4; ++mi)
#pragma unroll
            for (int ni = 0; ni < 4; ++ni)
                acc[mi][ni] = __builtin_amdgcn_mfma_f32_16x16x32_bf16(
                    af[mi], bfr[ni], acc[mi][ni], 0, 0, 0);
        __syncthreads();
    }
#pragma unroll
    for (int mi = 0; mi < 4; ++mi) {
#pragma unroll
        for (int r = 0; r < 4; ++r) {
            float v = FLT_MAX;
#pragma unroll
            for (int ni = 0; ni < 4; ++ni) {
                int gcol = mb + wcol * 64 + ni * 16 + l16;
                float d2 = fmaf(-2.0f, acc[mi][ni][r], 2.0f);
                v = fminf(v, (gcol < MN) ? d2 : FLT_MAX);
            }
            v = fminf(v, __shfl_xor(v, 1));
            v = fminf(v, __shfl_xor(v, 2));
            v = fminf(v, __shfl_xor(v, 4));
            v = fminf(v, __shfl_xor(v, 8));
            if (l16 == 0)
                atomicMin(&qmin[wrow * 64 + mi * 16 + quad * 4 + r], encf(v));
        }
    }
    __syncthreads();
    if (tid < 128) atomicMin(&dminEnc[qb + tid], qmin[tid]);
}

__global__ void finalize(const unsigned* __restrict__ dminEnc, float* __restrict__ out) {
    __shared__ float red[256];
    const int tid = threadIdx.x;
    float mx = 0.f;
    for (int i = tid; i < QN; i += 256) {
        float d2 = decf(dminEnc[i]);
        float d = sqrtf(fmaxf(d2, 0.f));
        out[i] = d;
        mx = fmaxf(mx, d);
    }
    red[tid] = mx;
    __syncthreads();
    for (int s = 128; s > 0; s >>= 1) {
        if (tid < s) red[tid] = fmaxf(red[tid], red[tid + s]);
        __syncthreads();
    }
    if (tid == 0) out[QN] = red[0];
}

extern "C" void kernel_launch(void* const* d_in, const int* in_sizes, int n_in,
                              void* d_out, int out_size, void* d_ws, size_t ws_size,
                              hipStream_t stream)
{
    const float* query  = (const float*)d_in[0];
    const float* memory = (const float*)d_in[1];
    float* out = (float*)d_out;

    const size_t memB_elems = (size_t)MP * DN;          // padded bf16 memory
    const size_t qB_elems   = (size_t)QN * DN;
    const size_t need = memB_elems * 2 + qB_elems * 2 + (size_t)QN * 4;

    if (ws_size >= need) {
        short* mB = (short*)d_ws;
        short* qB = mB + memB_elems;
        unsigned* dminEnc = (unsigned*)(qB + qB_elems);

        hipLaunchKernelGGL(init_min, dim3((QN + 255) / 256), dim3(256), 0, stream, dminEnc);
        {
            long nv = (long)MN * DN, nt = (long)memB_elems;
            int blocks = (int)((nt / 4 + 255) / 256);
            hipLaunchKernelGGL(cvt_bf16, dim3(blocks), dim3(256), 0, stream,
                               memory, mB, nv, nt);
        }
        {
            long nv = (long)qB_elems, nt = (long)qB_elems;
            int blocks = (int)((nt / 4 + 255) / 256);
            hipLaunchKernelGGL(cvt_bf16, dim3(blocks), dim3(256), 0, stream,
                               query, qB, nv, nt);
        }
        hipLaunchKernelGGL(nn_gemm_bf16_256, dim3(QN / 256, MP / 256), dim3(512), 0, stream,
                           qB, mB, dminEnc);
        hipLaunchKernelGGL(finalize, dim3(1), dim3(256), 0, stream, dminEnc, out);
    } else {
        unsigned* dminEnc = (unsigned*)d_ws;
        hipLaunchKernelGGL(init_min, dim3((QN + 255) / 256), dim3(256), 0, stream, dminEnc);
        hipLaunchKernelGGL(nn_gemm_f32, dim3(QN / 128, (MN + 127) / 128), dim3(256), 0, stream,
                           query, memory, dminEnc);
        hipLaunchKernelGGL(finalize, dim3(1), dim3(256), 0, stream, dminEnc, out);
    }
}